// Round 10
// baseline (4254.755 us; speedup 1.0000x reference)
//
#include <hip/hip_runtime.h>
#include <hip/hip_fp16.h>
#include <stdint.h>

#define T_STEPS 1024
#define HDIM    128
#define NT      256     // 4 waves/block, 1 wave/SIMD -> 512-reg unified budget
#define BS      16      // samples per block -> grid = 256/16 = 16 blocks

// MFMA-batched design (R10 = R9 resubmit; R9 died to container infra, not
// the kernel — audit found no fault/hang candidate):
//   D(16 samples x 16 gate-cols) = A(h^T: samples x K=128) x B(W^T) via
//   mfma_f32_16x16x32_f16, 4 K-tiles. N=512 gate-rows = 32 N-tiles.
//   wave w owns elements [32w, 32w+32): N-tiles {8g + 2w + d}, g=0..3 d=0..1.
//   lane: c = l&15 (gate-col within tile -> element e = 32w + 16d + c),
//         q = l>>4; C frag: row = 4q+r = sample (verified m89/m91 layout).
//   A frag: row=l&15=sample, k = 32kt + 8q + j (contig 8).
//   B frag: col=l&15, same k-range -> W[16*ntile + c][32kt + 8q ..+8].
// All 4 gates of an element live in ONE lane -> lane-local cell update.
// Weights: 3 matrices x 8 rows x 4 kt x 4 dw = 384 dw/lane, AGPR-eligible
// (MFMA reads AGPR natively — the register class the allocator kept
// exiling weights into through R2-R8; there it cost a move per dot2,
// here it is free). R7's 1-barrier pipeline: iter k does L2(k-1), L1(k).

typedef _Float16 f16x8 __attribute__((ext_vector_type(8)));
typedef float    f32x4 __attribute__((ext_vector_type(4)));
union U4H { uint4 u; f16x8 h; };
__device__ __forceinline__ f16x8 toh(uint4 u) { U4H x; x.u = u; return x.h; }

__device__ __forceinline__ uint32_t pk(float2 e) {
    return (uint32_t)__half_as_ushort(__float2half_rn(e.x)) |
           ((uint32_t)__half_as_ushort(__float2half_rn(e.y)) << 16);
}
__device__ __forceinline__ uint16_t f2h(float f) {
    return __half_as_ushort(__float2half_rn(f));
}
__device__ __forceinline__ float sigf(float x) {
    return 1.0f - __builtin_amdgcn_rcpf(__expf(x) + 1.0f);
}
__device__ __forceinline__ float tanhf_(float x) {
    return 1.0f - 2.0f * __builtin_amdgcn_rcpf(__expf(2.0f * x) + 1.0f);
}
__device__ __forceinline__ void cellup(float pi, float pf, float pg, float po,
                                       float& cc, float& hh) {
    float i_ = sigf(pi), f_ = sigf(pf), g_ = tanhf_(pg), o_ = sigf(po);
    cc = fmaf(f_, cc, i_ * g_);
    hh = o_ * tanhf_(cc);
}

#define SB() __builtin_amdgcn_sched_barrier(0)
#define PIN4(W) asm volatile("" : "+v"(W.x), "+v"(W.y), "+v"(W.z), "+v"(W.w))

#define MF(acc, A, W) acc = __builtin_amdgcn_mfma_f32_16x16x32_f16(toh(A), toh(W), acc, 0, 0, 0)

// pack 8 consecutive f32 at P+32*kt into 4 f16-pair dwords
#define LOADKT(V, P, kt) do { const float2* _r = (const float2*)((P) + 32*(kt)); \
    V = make_uint4(pk(_r[0]), pk(_r[1]), pk(_r[2]), pk(_r[3])); } while (0)
#define LOADROW(V0, V1, V2, V3, P) do {                                    \
    LOADKT(V0, P, 0); LOADKT(V1, P, 1); LOADKT(V2, P, 2); LOADKT(V3, P, 3);\
    PIN4(V0); PIN4(V1); PIN4(V2); PIN4(V3); SB(); } while (0)

// A-fragment read from sample-major f16 LDS (row stride 272 B: 256 + 16 pad
// -> 68 dwords, bank stride 4 -> 16 lanes cover 32 banks 2x: conflict-free)
#define RDH(V, BASE, kt) \
    V = *(const uint4*)((const char*)(BASE) + c*272 + (kt)*64 + q*16)

// reduce over the 16 c-lanes (lane bits 0..3): xor1/2 DPP, xor4/8 swizzle
#define RED16(v) do { int t_;                                              \
    t_ = __float_as_int(v);                                                \
    v += __int_as_float(__builtin_amdgcn_update_dpp(0, t_, 0xB1, 0xF, 0xF, true)); \
    t_ = __float_as_int(v);                                                \
    v += __int_as_float(__builtin_amdgcn_update_dpp(0, t_, 0x4E, 0xF, 0xF, true)); \
    t_ = __float_as_int(v);                                                \
    v += __int_as_float(__builtin_amdgcn_ds_swizzle(t_, 0x101F));          \
    t_ = __float_as_int(v);                                                \
    v += __int_as_float(__builtin_amdgcn_ds_swizzle(t_, 0x201F)); } while (0)

// L2 epilogue cell: gates from q-accs + bias2; publish f16 h2; out partial
#define EPI2(d, j, CC, UU) do { float hh_;                                 \
    cellup(qi##d[j] + B2##d.x, qf##d[j] + B2##d.y,                         \
           qg##d[j] + B2##d.z, qo##d[j] + B2##d.w, CC, hh_);               \
    Hw2[(4*q + (j))*136 + e##d] = f2h(hh_);                                \
    UU = fmaf(wo##d, hh_, UU); } while (0)

// L1 epilogue cell: gates from a-accs + x-term + bias1; publish f16 h1
#define EPI1(d, j, CC) do { float hh_;                                     \
    cellup(ai##d[j]  + fmaf(xc##j, WX##d.x, B1##d.x),                      \
           af##d[j]  + fmaf(xc##j, WX##d.y, B1##d.y),                      \
           agg##d[j] + fmaf(xc##j, WX##d.z, B1##d.z),                      \
           ao##d[j]  + fmaf(xc##j, WX##d.w, B1##d.w), CC, hh_);            \
    Hw1[(4*q + (j))*136 + e##d] = f2h(hh_); } while (0)

// one K-tile of MFMAs: 8 N-tiles (rows r = 2g+d)
#define MFL2A(kt) do {                                                     \
    MF(qi0, AH##kt, m2r0k##kt); MF(qi1, AH##kt, m2r1k##kt);                \
    MF(qf0, AH##kt, m2r2k##kt); MF(qf1, AH##kt, m2r3k##kt);                \
    MF(qg0, AH##kt, m2r4k##kt); MF(qg1, AH##kt, m2r5k##kt);                \
    MF(qo0, AH##kt, m2r6k##kt); MF(qo1, AH##kt, m2r7k##kt); } while (0)
#define MFL2B(kt) do {                                                     \
    MF(qi0, AG##kt, m3r0k##kt); MF(qi1, AG##kt, m3r1k##kt);                \
    MF(qf0, AG##kt, m3r2k##kt); MF(qf1, AG##kt, m3r3k##kt);                \
    MF(qg0, AG##kt, m3r4k##kt); MF(qg1, AG##kt, m3r5k##kt);                \
    MF(qo0, AG##kt, m3r6k##kt); MF(qo1, AG##kt, m3r7k##kt); } while (0)
#define MFL1(kt) do {                                                      \
    MF(ai0, AH##kt, m1r0k##kt); MF(ai1, AH##kt, m1r1k##kt);                \
    MF(af0, AH##kt, m1r2k##kt); MF(af1, AH##kt, m1r3k##kt);                \
    MF(agg0,AH##kt, m1r4k##kt); MF(agg1,AH##kt, m1r5k##kt);                \
    MF(ao0, AH##kt, m1r6k##kt); MF(ao1, AH##kt, m1r7k##kt); } while (0)

#define ROWP(W, g, d) ((W) + (size_t)((g)*128 + 32*w + 16*(d) + c) * HDIM + q*8)

__global__ __launch_bounds__(NT)
__attribute__((amdgpu_waves_per_eu(1, 1)))
void lstm_persistent(
    const float* __restrict__ x,
    const float* __restrict__ W_ih1, const float* __restrict__ W_hh1,
    const float* __restrict__ b_ih1, const float* __restrict__ b_hh1,
    const float* __restrict__ W_ih2, const float* __restrict__ W_hh2,
    const float* __restrict__ b_ih2, const float* __restrict__ b_hh2,
    const float* __restrict__ W_out, const float* __restrict__ b_out,
    float* __restrict__ out)
{
    const int b0  = blockIdx.x * BS;   // sample base
    const int tid = threadIdx.x;
    const int w   = tid >> 6;          // wave 0..3
    const int l   = tid & 63;
    const int c   = l & 15;            // gate-col within N-tile
    const int q   = l >> 4;            // quarter -> samples 4q..4q+3, k-group
    const int e0  = 32*w + c;          // owned elements
    const int e1  = e0 + 16;

    // h buffers: sample-major f16, row stride 136 u16 (272 B)
    __shared__ __align__(16) uint16_t Hb1[2][BS * 136];
    __shared__ __align__(16) uint16_t Hb2[2][BS * 136];
    __shared__ __align__(16) float4 bt1[HDIM];   // L1 bias  (i,f,g,o) per elem
    __shared__ __align__(16) float4 btw[HDIM];   // W_ih1    (i,f,g,o) per elem
    __shared__ __align__(16) float4 bt2[HDIM];   // L2 bias
    __shared__ float pbuf[2][4][BS];             // per-wave out partials, dbuf

    // ---- one-time: weight B-fragments -> 96 named uint4 (384 dw), fenced
    uint4 m1r0k0,m1r0k1,m1r0k2,m1r0k3, m1r1k0,m1r1k1,m1r1k2,m1r1k3;
    uint4 m1r2k0,m1r2k1,m1r2k2,m1r2k3, m1r3k0,m1r3k1,m1r3k2,m1r3k3;
    uint4 m1r4k0,m1r4k1,m1r4k2,m1r4k3, m1r5k0,m1r5k1,m1r5k2,m1r5k3;
    uint4 m1r6k0,m1r6k1,m1r6k2,m1r6k3, m1r7k0,m1r7k1,m1r7k2,m1r7k3;
    uint4 m2r0k0,m2r0k1,m2r0k2,m2r0k3, m2r1k0,m2r1k1,m2r1k2,m2r1k3;
    uint4 m2r2k0,m2r2k1,m2r2k2,m2r2k3, m2r3k0,m2r3k1,m2r3k2,m2r3k3;
    uint4 m2r4k0,m2r4k1,m2r4k2,m2r4k3, m2r5k0,m2r5k1,m2r5k2,m2r5k3;
    uint4 m2r6k0,m2r6k1,m2r6k2,m2r6k3, m2r7k0,m2r7k1,m2r7k2,m2r7k3;
    uint4 m3r0k0,m3r0k1,m3r0k2,m3r0k3, m3r1k0,m3r1k1,m3r1k2,m3r1k3;
    uint4 m3r2k0,m3r2k1,m3r2k2,m3r2k3, m3r3k0,m3r3k1,m3r3k2,m3r3k3;
    uint4 m3r4k0,m3r4k1,m3r4k2,m3r4k3, m3r5k0,m3r5k1,m3r5k2,m3r5k3;
    uint4 m3r6k0,m3r6k1,m3r6k2,m3r6k3, m3r7k0,m3r7k1,m3r7k2,m3r7k3;

    LOADROW(m1r0k0,m1r0k1,m1r0k2,m1r0k3, ROWP(W_hh1,0,0));
    LOADROW(m1r1k0,m1r1k1,m1r1k2,m1r1k3, ROWP(W_hh1,0,1));
    LOADROW(m1r2k0,m1r2k1,m1r2k2,m1r2k3, ROWP(W_hh1,1,0));
    LOADROW(m1r3k0,m1r3k1,m1r3k2,m1r3k3, ROWP(W_hh1,1,1));
    LOADROW(m1r4k0,m1r4k1,m1r4k2,m1r4k3, ROWP(W_hh1,2,0));
    LOADROW(m1r5k0,m1r5k1,m1r5k2,m1r5k3, ROWP(W_hh1,2,1));
    LOADROW(m1r6k0,m1r6k1,m1r6k2,m1r6k3, ROWP(W_hh1,3,0));
    LOADROW(m1r7k0,m1r7k1,m1r7k2,m1r7k3, ROWP(W_hh1,3,1));
    LOADROW(m2r0k0,m2r0k1,m2r0k2,m2r0k3, ROWP(W_ih2,0,0));
    LOADROW(m2r1k0,m2r1k1,m2r1k2,m2r1k3, ROWP(W_ih2,0,1));
    LOADROW(m2r2k0,m2r2k1,m2r2k2,m2r2k3, ROWP(W_ih2,1,0));
    LOADROW(m2r3k0,m2r3k1,m2r3k2,m2r3k3, ROWP(W_ih2,1,1));
    LOADROW(m2r4k0,m2r4k1,m2r4k2,m2r4k3, ROWP(W_ih2,2,0));
    LOADROW(m2r5k0,m2r5k1,m2r5k2,m2r5k3, ROWP(W_ih2,2,1));
    LOADROW(m2r6k0,m2r6k1,m2r6k2,m2r6k3, ROWP(W_ih2,3,0));
    LOADROW(m2r7k0,m2r7k1,m2r7k2,m2r7k3, ROWP(W_ih2,3,1));
    LOADROW(m3r0k0,m3r0k1,m3r0k2,m3r0k3, ROWP(W_hh2,0,0));
    LOADROW(m3r1k0,m3r1k1,m3r1k2,m3r1k3, ROWP(W_hh2,0,1));
    LOADROW(m3r2k0,m3r2k1,m3r2k2,m3r2k3, ROWP(W_hh2,1,0));
    LOADROW(m3r3k0,m3r3k1,m3r3k2,m3r3k3, ROWP(W_hh2,1,1));
    LOADROW(m3r4k0,m3r4k1,m3r4k2,m3r4k3, ROWP(W_hh2,2,0));
    LOADROW(m3r5k0,m3r5k1,m3r5k2,m3r5k3, ROWP(W_hh2,2,1));
    LOADROW(m3r6k0,m3r6k1,m3r6k2,m3r6k3, ROWP(W_hh2,3,0));
    LOADROW(m3r7k0,m3r7k1,m3r7k2,m3r7k3, ROWP(W_hh2,3,1));

    // ---- one-time: bias/x-weight tables, h zero-init
    if (tid < HDIM) {
        int ee = tid;
        bt1[ee] = make_float4(b_ih1[ee]     + b_hh1[ee],
                              b_ih1[ee+128] + b_hh1[ee+128],
                              b_ih1[ee+256] + b_hh1[ee+256],
                              b_ih1[ee+384] + b_hh1[ee+384]);
        btw[ee] = make_float4(W_ih1[ee], W_ih1[ee+128],
                              W_ih1[ee+256], W_ih1[ee+384]);
        bt2[ee] = make_float4(b_ih2[ee]     + b_hh2[ee],
                              b_ih2[ee+128] + b_hh2[ee+128],
                              b_ih2[ee+256] + b_hh2[ee+256],
                              b_ih2[ee+384] + b_hh2[ee+384]);
    }
    for (int i = tid; i < BS * 136; i += NT) {   // zero both dbufs (u32 view)
        ((uint32_t*)Hb1)[i] = 0u;
        ((uint32_t*)Hb2)[i] = 0u;
    }
    const float wo0 = W_out[e0], wo1 = W_out[e1];
    const float bo  = b_out[0];

    // cell state: lane holds (2 elems x 4 samples)
    float c1a0=0,c1a1=0,c1a2=0,c1a3=0, c1b0=0,c1b1=0,c1b2=0,c1b3=0;
    float c2a0=0,c2a1=0,c2a2=0,c2a3=0, c2b0=0,c2b1=0,c2b2=0,c2b3=0;

    // x: lane's 4 samples (4q+j), prefetched one step ahead
    const float* xr0 = x + (size_t)(b0 + 4*q + 0) * T_STEPS;
    const float* xr1 = x + (size_t)(b0 + 4*q + 1) * T_STEPS;
    const float* xr2 = x + (size_t)(b0 + 4*q + 2) * T_STEPS;
    const float* xr3 = x + (size_t)(b0 + 4*q + 3) * T_STEPS;
    float xc0 = xr0[0], xc1 = xr1[0], xc2 = xr2[0], xc3 = xr3[0];

    __syncthreads();

    // Iteration k: computes L2(k-1) -> h2(k-1)/out(k-1), then L1(k) -> h1(k).
    for (int k = 0; k <= T_STEPS; ++k) {
        const int rb = k & 1, wb = rb ^ 1;

        // ---- store out(k-2) (partials published before last barrier)
        if (k >= 2 && tid < BS) {
            int p = rb ^ 1;
            float s_ = pbuf[p][0][tid] + pbuf[p][1][tid]
                     + pbuf[p][2][tid] + pbuf[p][3][tid];
            out[(size_t)(b0 + tid) * T_STEPS + (k - 2)] = s_ + bo;
        }

        // ---- prefetch x(k+1)
        int kn = (k < T_STEPS - 1) ? (k + 1) : (T_STEPS - 1);
        float xn0 = xr0[kn], xn1 = xr1[kn], xn2 = xr2[kn], xn3 = xr3[kn];

        // ---- A-fragments: h1(k-1) (feeds L2-ih2 AND L1), h2(k-2)
        uint4 AH0, AH1, AH2, AH3, AG0, AG1, AG2, AG3;
        RDH(AH0, Hb1[rb], 0); RDH(AH1, Hb1[rb], 1);
        RDH(AH2, Hb1[rb], 2); RDH(AH3, Hb1[rb], 3);
        RDH(AG0, Hb2[rb], 0); RDH(AG1, Hb2[rb], 1);
        RDH(AG2, Hb2[rb], 2); RDH(AG3, Hb2[rb], 3);

        // ---- L2(k-1): gates2 = W_ih2.h1(k-1) + W_hh2.h2(k-2)  (64 MFMA)
        f32x4 qi0 = 0, qi1 = 0, qf0 = 0, qf1 = 0;
        f32x4 qg0 = 0, qg1 = 0, qo0 = 0, qo1 = 0;
        MFL2A(0); MFL2B(0); MFL2A(1); MFL2B(1);
        MFL2A(2); MFL2B(2); MFL2A(3); MFL2B(3);

        int te0 = e0, te1 = e1;
        asm volatile("" : "+v"(te0), "+v"(te1));   // keep table reads in-loop

        if (k > 0) {   // epilogue 2: h2(k-1), out(k-1) partials
            float4 B20 = bt2[te0], B21 = bt2[te1];
            uint16_t* Hw2 = Hb2[wb];
            float u0 = 0.f, u1 = 0.f, u2 = 0.f, u3 = 0.f;
            EPI2(0,0,c2a0,u0); EPI2(0,1,c2a1,u1); EPI2(0,2,c2a2,u2); EPI2(0,3,c2a3,u3);
            EPI2(1,0,c2b0,u0); EPI2(1,1,c2b1,u1); EPI2(1,2,c2b2,u2); EPI2(1,3,c2b3,u3);
            RED16(u0); RED16(u1); RED16(u2); RED16(u3);
            if (c == 0) {
                pbuf[rb][w][4*q + 0] = u0; pbuf[rb][w][4*q + 1] = u1;
                pbuf[rb][w][4*q + 2] = u2; pbuf[rb][w][4*q + 3] = u3;
            }
        }

        // ---- L1(k): gates1 = W_hh1.h1(k-1)  (32 MFMA; AH frags reused)
        f32x4 ai0 = 0, ai1 = 0, af0 = 0, af1 = 0;
        f32x4 agg0 = 0, agg1 = 0, ao0 = 0, ao1 = 0;
        MFL1(0); MFL1(1); MFL1(2); MFL1(3);

        {   // epilogue 1: h1(k) with x-term + bias
            float4 B10 = bt1[te0], B11 = bt1[te1];
            float4 WX0 = btw[te0], WX1 = btw[te1];
            uint16_t* Hw1 = Hb1[wb];
            EPI1(0,0,c1a0); EPI1(0,1,c1a1); EPI1(0,2,c1a2); EPI1(0,3,c1a3);
            EPI1(1,0,c1b0); EPI1(1,1,c1b1); EPI1(1,2,c1b2); EPI1(1,3,c1b3);
        }

        __syncthreads();   // single barrier: publish h1(k), h2(k-1), partials
        xc0 = xn0; xc1 = xn1; xc2 = xn2; xc3 = xn3;
    }

    // ---- drain: out(T-1) (partials written at k=T, parity T&1)
    if (tid < BS) {
        int p = T_STEPS & 1;
        float s_ = pbuf[p][0][tid] + pbuf[p][1][tid]
                 + pbuf[p][2][tid] + pbuf[p][3][tid];
        out[(size_t)(b0 + tid) * T_STEPS + (T_STEPS - 1)] = s_ + bo;
    }
}

extern "C" void kernel_launch(void* const* d_in, const int* in_sizes, int n_in,
                              void* d_out, int out_size, void* d_ws, size_t ws_size,
                              hipStream_t stream) {
    const float* x     = (const float*)d_in[0];
    const float* W_ih1 = (const float*)d_in[1];
    const float* W_hh1 = (const float*)d_in[2];
    const float* b_ih1 = (const float*)d_in[3];
    const float* b_hh1 = (const float*)d_in[4];
    const float* W_ih2 = (const float*)d_in[5];
    const float* W_hh2 = (const float*)d_in[6];
    const float* b_ih2 = (const float*)d_in[7];
    const float* b_hh2 = (const float*)d_in[8];
    const float* W_out = (const float*)d_in[9];
    const float* b_out = (const float*)d_in[10];
    float* out = (float*)d_out;

    const int B  = in_sizes[0] / T_STEPS;   // 256
    const int NB = B / BS;                  // 16 blocks
    hipLaunchKernelGGL(lstm_persistent, dim3(NB), dim3(NT), 0, stream,
                       x, W_ih1, W_hh1, b_ih1, b_hh1,
                       W_ih2, W_hh2, b_ih2, b_hh2, W_out, b_out, out);
}

// Round 11
// 2836.217 us; speedup vs baseline: 1.5002x; 1.5002x over previous
//
#include <hip/hip_runtime.h>
#include <hip/hip_fp16.h>
#include <stdint.h>

#define T_STEPS 1024
#define HDIM    128
#define NT      256     // 4 waves/block, 1 wave/SIMD -> 512-reg unified budget
#define BS      16      // samples per block -> grid = 256/16 = 16 blocks

// MFMA-batched design (R11 = R10 + class-split register pins):
//   R10 post-mortem: PIN4's "v" constraint demanded all 384 weight dwords
//   be ARCH VGPRs simultaneously (cap 256) -> allocator spilled ~41
//   dw/thread to scratch, reloaded EVERY step at L2 latency with 1
//   wave/SIMD -> 9830 cyc/step. Fix: pin L2 weights (256 dw) with the
//   "a" (AGPR) constraint — MFMA reads AGPR operands natively, and 256
//   exactly fills the AGPR half; L1 weights (128 dw) stay "v" in arch
//   (128 + ~110 working set <= 256). Total 494 <= 512 unified.
//
//   Geometry (verified correct in R10, absmax 1.2e-4):
//   D(16 samples x 16 gate-cols) = A(h^T) x B(W^T), mfma_f32_16x16x32_f16.
//   wave w owns elements [32w,32w+32); lane: c=l&15 (gate-col), q=l>>4.
//   C frag row = 4q+r = sample (m89/m91 layout). All 4 gates of an
//   element live in ONE lane -> lane-local cell update.
//   R7's 1-barrier pipeline: iter k does L2(k-1) then L1(k).

typedef _Float16 f16x8 __attribute__((ext_vector_type(8)));
typedef float    f32x4 __attribute__((ext_vector_type(4)));
union U4H { uint4 u; f16x8 h; };
__device__ __forceinline__ f16x8 toh(uint4 u) { U4H x; x.u = u; return x.h; }

__device__ __forceinline__ uint32_t pk(float2 e) {
    return (uint32_t)__half_as_ushort(__float2half_rn(e.x)) |
           ((uint32_t)__half_as_ushort(__float2half_rn(e.y)) << 16);
}
__device__ __forceinline__ uint16_t f2h(float f) {
    return __half_as_ushort(__float2half_rn(f));
}
__device__ __forceinline__ float sigf(float x) {
    return 1.0f - __builtin_amdgcn_rcpf(__expf(x) + 1.0f);
}
__device__ __forceinline__ float tanhf_(float x) {
    return 1.0f - 2.0f * __builtin_amdgcn_rcpf(__expf(2.0f * x) + 1.0f);
}
__device__ __forceinline__ void cellup(float pi, float pf, float pg, float po,
                                       float& cc, float& hh) {
    float i_ = sigf(pi), f_ = sigf(pf), g_ = tanhf_(pg), o_ = sigf(po);
    cc = fmaf(f_, cc, i_ * g_);
    hh = o_ * tanhf_(cc);
}

#define SB() __builtin_amdgcn_sched_barrier(0)
// arch-VGPR pin (L1 weights: these + working set fit the 256 arch cap)
#define PIN4V(W) asm volatile("" : "+v"(W.x), "+v"(W.y), "+v"(W.z), "+v"(W.w))
// AGPR pin (L2 weights: MFMA reads AGPR natively; 64 uint4 = 256 dw = full
// AGPR half). "a" = AGPR constraint, supported gfx908+.
#define PIN4A(W) asm volatile("" : "+a"(W.x), "+a"(W.y), "+a"(W.z), "+a"(W.w))

#define MF(acc, A, W) acc = __builtin_amdgcn_mfma_f32_16x16x32_f16(toh(A), toh(W), acc, 0, 0, 0)

// pack 8 consecutive f32 at P+32*kt into 4 f16-pair dwords
#define LOADKT(V, P, kt) do { const float2* _r = (const float2*)((P) + 32*(kt)); \
    V = make_uint4(pk(_r[0]), pk(_r[1]), pk(_r[2]), pk(_r[3])); } while (0)
#define LOADROWV(V0, V1, V2, V3, P) do {                                   \
    LOADKT(V0, P, 0); LOADKT(V1, P, 1); LOADKT(V2, P, 2); LOADKT(V3, P, 3);\
    PIN4V(V0); PIN4V(V1); PIN4V(V2); PIN4V(V3); SB(); } while (0)
#define LOADROWA(V0, V1, V2, V3, P) do {                                   \
    LOADKT(V0, P, 0); LOADKT(V1, P, 1); LOADKT(V2, P, 2); LOADKT(V3, P, 3);\
    PIN4A(V0); PIN4A(V1); PIN4A(V2); PIN4A(V3); SB(); } while (0)

// A-fragment read from sample-major f16 LDS (row stride 272 B: 256 + 16 pad
// -> 68 dwords, bank stride 4 -> 16 lanes cover 32 banks 2x: conflict-free)
#define RDH(V, BASE, kt) \
    V = *(const uint4*)((const char*)(BASE) + c*272 + (kt)*64 + q*16)

// reduce over the 16 c-lanes (lane bits 0..3): xor1/2 DPP, xor4/8 swizzle
#define RED16(v) do { int t_;                                              \
    t_ = __float_as_int(v);                                                \
    v += __int_as_float(__builtin_amdgcn_update_dpp(0, t_, 0xB1, 0xF, 0xF, true)); \
    t_ = __float_as_int(v);                                                \
    v += __int_as_float(__builtin_amdgcn_update_dpp(0, t_, 0x4E, 0xF, 0xF, true)); \
    t_ = __float_as_int(v);                                                \
    v += __int_as_float(__builtin_amdgcn_ds_swizzle(t_, 0x101F));          \
    t_ = __float_as_int(v);                                                \
    v += __int_as_float(__builtin_amdgcn_ds_swizzle(t_, 0x201F)); } while (0)

// L2 epilogue cell: gates from q-accs + bias2; publish f16 h2; out partial
#define EPI2(d, j, CC, UU) do { float hh_;                                 \
    cellup(qi##d[j] + B2##d.x, qf##d[j] + B2##d.y,                         \
           qg##d[j] + B2##d.z, qo##d[j] + B2##d.w, CC, hh_);               \
    Hw2[(4*q + (j))*136 + e##d] = f2h(hh_);                                \
    UU = fmaf(wo##d, hh_, UU); } while (0)

// L1 epilogue cell: gates from a-accs + x-term + bias1; publish f16 h1
#define EPI1(d, j, CC) do { float hh_;                                     \
    cellup(ai##d[j]  + fmaf(xc##j, WX##d.x, B1##d.x),                      \
           af##d[j]  + fmaf(xc##j, WX##d.y, B1##d.y),                      \
           agg##d[j] + fmaf(xc##j, WX##d.z, B1##d.z),                      \
           ao##d[j]  + fmaf(xc##j, WX##d.w, B1##d.w), CC, hh_);            \
    Hw1[(4*q + (j))*136 + e##d] = f2h(hh_); } while (0)

// one K-tile of MFMAs: 8 N-tiles (rows r = 2g+d)
#define MFL2A(kt) do {                                                     \
    MF(qi0, AH##kt, m2r0k##kt); MF(qi1, AH##kt, m2r1k##kt);                \
    MF(qf0, AH##kt, m2r2k##kt); MF(qf1, AH##kt, m2r3k##kt);                \
    MF(qg0, AH##kt, m2r4k##kt); MF(qg1, AH##kt, m2r5k##kt);                \
    MF(qo0, AH##kt, m2r6k##kt); MF(qo1, AH##kt, m2r7k##kt); } while (0)
#define MFL2B(kt) do {                                                     \
    MF(qi0, AG##kt, m3r0k##kt); MF(qi1, AG##kt, m3r1k##kt);                \
    MF(qf0, AG##kt, m3r2k##kt); MF(qf1, AG##kt, m3r3k##kt);                \
    MF(qg0, AG##kt, m3r4k##kt); MF(qg1, AG##kt, m3r5k##kt);                \
    MF(qo0, AG##kt, m3r6k##kt); MF(qo1, AG##kt, m3r7k##kt); } while (0)
#define MFL1(kt) do {                                                      \
    MF(ai0, AH##kt, m1r0k##kt); MF(ai1, AH##kt, m1r1k##kt);                \
    MF(af0, AH##kt, m1r2k##kt); MF(af1, AH##kt, m1r3k##kt);                \
    MF(agg0,AH##kt, m1r4k##kt); MF(agg1,AH##kt, m1r5k##kt);                \
    MF(ao0, AH##kt, m1r6k##kt); MF(ao1, AH##kt, m1r7k##kt); } while (0)

#define ROWP(W, g, d) ((W) + (size_t)((g)*128 + 32*w + 16*(d) + c) * HDIM + q*8)

__global__ __launch_bounds__(NT)
__attribute__((amdgpu_waves_per_eu(1, 1)))
void lstm_persistent(
    const float* __restrict__ x,
    const float* __restrict__ W_ih1, const float* __restrict__ W_hh1,
    const float* __restrict__ b_ih1, const float* __restrict__ b_hh1,
    const float* __restrict__ W_ih2, const float* __restrict__ W_hh2,
    const float* __restrict__ b_ih2, const float* __restrict__ b_hh2,
    const float* __restrict__ W_out, const float* __restrict__ b_out,
    float* __restrict__ out)
{
    const int b0  = blockIdx.x * BS;   // sample base
    const int tid = threadIdx.x;
    const int w   = tid >> 6;          // wave 0..3
    const int l   = tid & 63;
    const int c   = l & 15;            // gate-col within N-tile
    const int q   = l >> 4;            // quarter -> samples 4q..4q+3, k-group
    const int e0  = 32*w + c;          // owned elements
    const int e1  = e0 + 16;

    // h buffers: sample-major f16, row stride 136 u16 (272 B)
    __shared__ __align__(16) uint16_t Hb1[2][BS * 136];
    __shared__ __align__(16) uint16_t Hb2[2][BS * 136];
    __shared__ __align__(16) float4 bt1[HDIM];   // L1 bias  (i,f,g,o) per elem
    __shared__ __align__(16) float4 btw[HDIM];   // W_ih1    (i,f,g,o) per elem
    __shared__ __align__(16) float4 bt2[HDIM];   // L2 bias
    __shared__ float pbuf[2][4][BS];             // per-wave out partials, dbuf

    // ---- one-time: weight B-fragments. L1 (m1*, 128 dw) -> arch VGPR;
    // L2 (m2*/m3*, 256 dw) -> AGPR (MFMA-native, fills the AGPR half).
    uint4 m1r0k0,m1r0k1,m1r0k2,m1r0k3, m1r1k0,m1r1k1,m1r1k2,m1r1k3;
    uint4 m1r2k0,m1r2k1,m1r2k2,m1r2k3, m1r3k0,m1r3k1,m1r3k2,m1r3k3;
    uint4 m1r4k0,m1r4k1,m1r4k2,m1r4k3, m1r5k0,m1r5k1,m1r5k2,m1r5k3;
    uint4 m1r6k0,m1r6k1,m1r6k2,m1r6k3, m1r7k0,m1r7k1,m1r7k2,m1r7k3;
    uint4 m2r0k0,m2r0k1,m2r0k2,m2r0k3, m2r1k0,m2r1k1,m2r1k2,m2r1k3;
    uint4 m2r2k0,m2r2k1,m2r2k2,m2r2k3, m2r3k0,m2r3k1,m2r3k2,m2r3k3;
    uint4 m2r4k0,m2r4k1,m2r4k2,m2r4k3, m2r5k0,m2r5k1,m2r5k2,m2r5k3;
    uint4 m2r6k0,m2r6k1,m2r6k2,m2r6k3, m2r7k0,m2r7k1,m2r7k2,m2r7k3;
    uint4 m3r0k0,m3r0k1,m3r0k2,m3r0k3, m3r1k0,m3r1k1,m3r1k2,m3r1k3;
    uint4 m3r2k0,m3r2k1,m3r2k2,m3r2k3, m3r3k0,m3r3k1,m3r3k2,m3r3k3;
    uint4 m3r4k0,m3r4k1,m3r4k2,m3r4k3, m3r5k0,m3r5k1,m3r5k2,m3r5k3;
    uint4 m3r6k0,m3r6k1,m3r6k2,m3r6k3, m3r7k0,m3r7k1,m3r7k2,m3r7k3;

    LOADROWV(m1r0k0,m1r0k1,m1r0k2,m1r0k3, ROWP(W_hh1,0,0));
    LOADROWV(m1r1k0,m1r1k1,m1r1k2,m1r1k3, ROWP(W_hh1,0,1));
    LOADROWV(m1r2k0,m1r2k1,m1r2k2,m1r2k3, ROWP(W_hh1,1,0));
    LOADROWV(m1r3k0,m1r3k1,m1r3k2,m1r3k3, ROWP(W_hh1,1,1));
    LOADROWV(m1r4k0,m1r4k1,m1r4k2,m1r4k3, ROWP(W_hh1,2,0));
    LOADROWV(m1r5k0,m1r5k1,m1r5k2,m1r5k3, ROWP(W_hh1,2,1));
    LOADROWV(m1r6k0,m1r6k1,m1r6k2,m1r6k3, ROWP(W_hh1,3,0));
    LOADROWV(m1r7k0,m1r7k1,m1r7k2,m1r7k3, ROWP(W_hh1,3,1));
    LOADROWA(m2r0k0,m2r0k1,m2r0k2,m2r0k3, ROWP(W_ih2,0,0));
    LOADROWA(m2r1k0,m2r1k1,m2r1k2,m2r1k3, ROWP(W_ih2,0,1));
    LOADROWA(m2r2k0,m2r2k1,m2r2k2,m2r2k3, ROWP(W_ih2,1,0));
    LOADROWA(m2r3k0,m2r3k1,m2r3k2,m2r3k3, ROWP(W_ih2,1,1));
    LOADROWA(m2r4k0,m2r4k1,m2r4k2,m2r4k3, ROWP(W_ih2,2,0));
    LOADROWA(m2r5k0,m2r5k1,m2r5k2,m2r5k3, ROWP(W_ih2,2,1));
    LOADROWA(m2r6k0,m2r6k1,m2r6k2,m2r6k3, ROWP(W_ih2,3,0));
    LOADROWA(m2r7k0,m2r7k1,m2r7k2,m2r7k3, ROWP(W_ih2,3,1));
    LOADROWA(m3r0k0,m3r0k1,m3r0k2,m3r0k3, ROWP(W_hh2,0,0));
    LOADROWA(m3r1k0,m3r1k1,m3r1k2,m3r1k3, ROWP(W_hh2,0,1));
    LOADROWA(m3r2k0,m3r2k1,m3r2k2,m3r2k3, ROWP(W_hh2,1,0));
    LOADROWA(m3r3k0,m3r3k1,m3r3k2,m3r3k3, ROWP(W_hh2,1,1));
    LOADROWA(m3r4k0,m3r4k1,m3r4k2,m3r4k3, ROWP(W_hh2,2,0));
    LOADROWA(m3r5k0,m3r5k1,m3r5k2,m3r5k3, ROWP(W_hh2,2,1));
    LOADROWA(m3r6k0,m3r6k1,m3r6k2,m3r6k3, ROWP(W_hh2,3,0));
    LOADROWA(m3r7k0,m3r7k1,m3r7k2,m3r7k3, ROWP(W_hh2,3,1));

    // ---- one-time: bias/x-weight tables, h zero-init
    if (tid < HDIM) {
        int ee = tid;
        bt1[ee] = make_float4(b_ih1[ee]     + b_hh1[ee],
                              b_ih1[ee+128] + b_hh1[ee+128],
                              b_ih1[ee+256] + b_hh1[ee+256],
                              b_ih1[ee+384] + b_hh1[ee+384]);
        btw[ee] = make_float4(W_ih1[ee], W_ih1[ee+128],
                              W_ih1[ee+256], W_ih1[ee+384]);
        bt2[ee] = make_float4(b_ih2[ee]     + b_hh2[ee],
                              b_ih2[ee+128] + b_hh2[ee+128],
                              b_ih2[ee+256] + b_hh2[ee+256],
                              b_ih2[ee+384] + b_hh2[ee+384]);
    }
    for (int i = tid; i < BS * 136; i += NT) {   // zero both dbufs (u32 view)
        ((uint32_t*)Hb1)[i] = 0u;
        ((uint32_t*)Hb2)[i] = 0u;
    }
    const float wo0 = W_out[e0], wo1 = W_out[e1];
    const float bo  = b_out[0];

    // cell state: lane holds (2 elems x 4 samples)
    float c1a0=0,c1a1=0,c1a2=0,c1a3=0, c1b0=0,c1b1=0,c1b2=0,c1b3=0;
    float c2a0=0,c2a1=0,c2a2=0,c2a3=0, c2b0=0,c2b1=0,c2b2=0,c2b3=0;

    // x: lane's 4 samples (4q+j), prefetched one step ahead
    const float* xr0 = x + (size_t)(b0 + 4*q + 0) * T_STEPS;
    const float* xr1 = x + (size_t)(b0 + 4*q + 1) * T_STEPS;
    const float* xr2 = x + (size_t)(b0 + 4*q + 2) * T_STEPS;
    const float* xr3 = x + (size_t)(b0 + 4*q + 3) * T_STEPS;
    float xc0 = xr0[0], xc1 = xr1[0], xc2 = xr2[0], xc3 = xr3[0];

    __syncthreads();

    // Iteration k: computes L2(k-1) -> h2(k-1)/out(k-1), then L1(k) -> h1(k).
    for (int k = 0; k <= T_STEPS; ++k) {
        const int rb = k & 1, wb = rb ^ 1;

        // ---- store out(k-2) (partials published before last barrier)
        if (k >= 2 && tid < BS) {
            int p = rb ^ 1;
            float s_ = pbuf[p][0][tid] + pbuf[p][1][tid]
                     + pbuf[p][2][tid] + pbuf[p][3][tid];
            out[(size_t)(b0 + tid) * T_STEPS + (k - 2)] = s_ + bo;
        }

        // ---- prefetch x(k+1)
        int kn = (k < T_STEPS - 1) ? (k + 1) : (T_STEPS - 1);
        float xn0 = xr0[kn], xn1 = xr1[kn], xn2 = xr2[kn], xn3 = xr3[kn];

        // ---- A-fragments: h1(k-1) (feeds L2-ih2 AND L1), h2(k-2)
        uint4 AH0, AH1, AH2, AH3, AG0, AG1, AG2, AG3;
        RDH(AH0, Hb1[rb], 0); RDH(AH1, Hb1[rb], 1);
        RDH(AH2, Hb1[rb], 2); RDH(AH3, Hb1[rb], 3);
        RDH(AG0, Hb2[rb], 0); RDH(AG1, Hb2[rb], 1);
        RDH(AG2, Hb2[rb], 2); RDH(AG3, Hb2[rb], 3);

        // ---- L2(k-1): gates2 = W_ih2.h1(k-1) + W_hh2.h2(k-2)  (64 MFMA)
        f32x4 qi0 = 0, qi1 = 0, qf0 = 0, qf1 = 0;
        f32x4 qg0 = 0, qg1 = 0, qo0 = 0, qo1 = 0;
        MFL2A(0); MFL2B(0); MFL2A(1); MFL2B(1);
        MFL2A(2); MFL2B(2); MFL2A(3); MFL2B(3);

        int te0 = e0, te1 = e1;
        asm volatile("" : "+v"(te0), "+v"(te1));   // keep table reads in-loop

        if (k > 0) {   // epilogue 2: h2(k-1), out(k-1) partials
            float4 B20 = bt2[te0], B21 = bt2[te1];
            uint16_t* Hw2 = Hb2[wb];
            float u0 = 0.f, u1 = 0.f, u2 = 0.f, u3 = 0.f;
            EPI2(0,0,c2a0,u0); EPI2(0,1,c2a1,u1); EPI2(0,2,c2a2,u2); EPI2(0,3,c2a3,u3);
            EPI2(1,0,c2b0,u0); EPI2(1,1,c2b1,u1); EPI2(1,2,c2b2,u2); EPI2(1,3,c2b3,u3);
            RED16(u0); RED16(u1); RED16(u2); RED16(u3);
            if (c == 0) {
                pbuf[rb][w][4*q + 0] = u0; pbuf[rb][w][4*q + 1] = u1;
                pbuf[rb][w][4*q + 2] = u2; pbuf[rb][w][4*q + 3] = u3;
            }
        }

        // ---- L1(k): gates1 = W_hh1.h1(k-1)  (32 MFMA; AH frags reused)
        f32x4 ai0 = 0, ai1 = 0, af0 = 0, af1 = 0;
        f32x4 agg0 = 0, agg1 = 0, ao0 = 0, ao1 = 0;
        MFL1(0); MFL1(1); MFL1(2); MFL1(3);

        {   // epilogue 1: h1(k) with x-term + bias
            float4 B10 = bt1[te0], B11 = bt1[te1];
            float4 WX0 = btw[te0], WX1 = btw[te1];
            uint16_t* Hw1 = Hb1[wb];
            EPI1(0,0,c1a0); EPI1(0,1,c1a1); EPI1(0,2,c1a2); EPI1(0,3,c1a3);
            EPI1(1,0,c1b0); EPI1(1,1,c1b1); EPI1(1,2,c1b2); EPI1(1,3,c1b3);
        }

        __syncthreads();   // single barrier: publish h1(k), h2(k-1), partials
        xc0 = xn0; xc1 = xn1; xc2 = xn2; xc3 = xn3;
    }

    // ---- drain: out(T-1) (partials written at k=T, parity T&1)
    if (tid < BS) {
        int p = T_STEPS & 1;
        float s_ = pbuf[p][0][tid] + pbuf[p][1][tid]
                 + pbuf[p][2][tid] + pbuf[p][3][tid];
        out[(size_t)(b0 + tid) * T_STEPS + (T_STEPS - 1)] = s_ + bo;
    }
}

extern "C" void kernel_launch(void* const* d_in, const int* in_sizes, int n_in,
                              void* d_out, int out_size, void* d_ws, size_t ws_size,
                              hipStream_t stream) {
    const float* x     = (const float*)d_in[0];
    const float* W_ih1 = (const float*)d_in[1];
    const float* W_hh1 = (const float*)d_in[2];
    const float* b_ih1 = (const float*)d_in[3];
    const float* b_hh1 = (const float*)d_in[4];
    const float* W_ih2 = (const float*)d_in[5];
    const float* W_hh2 = (const float*)d_in[6];
    const float* b_ih2 = (const float*)d_in[7];
    const float* b_hh2 = (const float*)d_in[8];
    const float* W_out = (const float*)d_in[9];
    const float* b_out = (const float*)d_in[10];
    float* out = (float*)d_out;

    const int B  = in_sizes[0] / T_STEPS;   // 256
    const int NB = B / BS;                  // 16 blocks
    hipLaunchKernelGGL(lstm_persistent, dim3(NB), dim3(NT), 0, stream,
                       x, W_ih1, W_hh1, b_ih1, b_hh1,
                       W_ih2, W_hh2, b_ih2, b_hh2, W_out, b_out, out);
}

// Round 12
// 1593.834 us; speedup vs baseline: 2.6695x; 1.7795x over previous
//
#include <hip/hip_runtime.h>
#include <hip/hip_fp16.h>
#include <stdint.h>

#define T_STEPS 1024
#define HDIM    128
#define NT      512

// K-sliced, single-barrier pipelined design (R12 = R7 + critical-path shave):
//   wave w = tid>>6 (0..7), lane l = tid&63
//   slice   s = l & 3        -> h columns [32s, 32s+32)
//   element e = 16w + (l>>2) (0..127)
// Iteration k fuses: gates1(k)   = W_hh1*h1(k-1)            (+ x(k), bias)
//                    gates2(k-1) = W_ih2*h1(k-1) + W_hh2*h2(k-2)
// One 192-dot block (8 indep acc chains), two epilogues, ONE barrier.
// R12 deltas vs R7 (1681 us verified):
//  - L1 bias/x-weight hoisted to 8 persistent regs (R7's LDS-table reads
//    could never be hoisted past __syncthreads -> they serialized epi1).
//  - out(k-2) store moved after the dot block (was at step head, its pbuf
//    read + shuffles delayed first dot issue).
//  - m1 -> m2 -> m3 dot order so epi1 (m1-only) overlaps m2/m3 dots.
// MFMA arc (R9-R11) abandoned: grid=16 blocks concentrates the fixed
// per-step epilogue on 16 CUs (~640 cyc/SIMD) vs 256 CUs here (~40).

typedef _Float16 v2h __attribute__((ext_vector_type(2)));
union HU { uint32_t u; v2h v; };

__device__ __forceinline__ float dot2h(uint32_t a, uint32_t b, float c) {
    HU ua, ub; ua.u = a; ub.u = b;
    return __builtin_amdgcn_fdot2(ua.v, ub.v, c, false);  // v_dot2_f32_f16
}
__device__ __forceinline__ uint32_t packh2f(float2 e) {
    return (uint32_t)__half_as_ushort(__float2half_rn(e.x)) |
           ((uint32_t)__half_as_ushort(__float2half_rn(e.y)) << 16);
}
__device__ __forceinline__ uint16_t f2h(float f) {
    return __half_as_ushort(__float2half_rn(f));
}
// act(a,1)=sigmoid(a); act(a,2)=tanh(a)
__device__ __forceinline__ float actf(float a, float m) {
    return 1.0f - m * __builtin_amdgcn_rcpf(__expf(m * a) + 1.0f);
}
// reduce over the 4 slice-lanes (lane bits 0..1): two DPP quad-perm adds.
__device__ __forceinline__ float red2(float v) {
    int iv = __float_as_int(v);
    v += __int_as_float(__builtin_amdgcn_update_dpp(0, iv, 0xB1, 0xF, 0xF, true)); // xor1
    iv = __float_as_int(v);
    v += __int_as_float(__builtin_amdgcn_update_dpp(0, iv, 0x4E, 0xF, 0xF, true)); // xor2
    return v;
}

#define SB() __builtin_amdgcn_sched_barrier(0)
#define PIN4(W) asm volatile("" : "+v"(W.x), "+v"(W.y), "+v"(W.z), "+v"(W.w))

// pack 32 consecutive floats at P into 4 uint4 of f16 pairs
#define SETW16(Wa, Wb, Wc, Wd, P) do { const float2* _r = (const float2*)(P); \
    Wa = make_uint4(packh2f(_r[0]),  packh2f(_r[1]),                       \
                    packh2f(_r[2]),  packh2f(_r[3]));                      \
    Wb = make_uint4(packh2f(_r[4]),  packh2f(_r[5]),                       \
                    packh2f(_r[6]),  packh2f(_r[7]));                      \
    Wc = make_uint4(packh2f(_r[8]),  packh2f(_r[9]),                       \
                    packh2f(_r[10]), packh2f(_r[11]));                     \
    Wd = make_uint4(packh2f(_r[12]), packh2f(_r[13]),                      \
                    packh2f(_r[14]), packh2f(_r[15])); } while (0)

// row pack + immediate pin + scheduling fence: caps init pressure spike.
#define ROW(Wa, Wb, Wc, Wd, P) do {                                        \
    SETW16(Wa, Wb, Wc, Wd, P);                                             \
    PIN4(Wa); PIN4(Wb); PIN4(Wc); PIN4(Wd); SB(); } while (0)

// 8 dot2s: one weight pair (2 uint4 = 16 cols) vs h pair
#define DOT8(Wa, Wb, H0, H1, acc) do {                                     \
    acc = dot2h(Wa.x, H0.x, acc); acc = dot2h(Wa.y, H0.y, acc);            \
    acc = dot2h(Wa.z, H0.z, acc); acc = dot2h(Wa.w, H0.w, acc);            \
    acc = dot2h(Wb.x, H1.x, acc); acc = dot2h(Wb.y, H1.y, acc);            \
    acc = dot2h(Wb.z, H1.z, acc); acc = dot2h(Wb.w, H1.w, acc); } while (0)

__global__ __launch_bounds__(NT)
__attribute__((amdgpu_waves_per_eu(2, 2)))
void lstm_persistent(
    const float* __restrict__ x,
    const float* __restrict__ W_ih1, const float* __restrict__ W_hh1,
    const float* __restrict__ b_ih1, const float* __restrict__ b_hh1,
    const float* __restrict__ W_ih2, const float* __restrict__ W_hh2,
    const float* __restrict__ b_ih2, const float* __restrict__ b_hh2,
    const float* __restrict__ W_out, const float* __restrict__ b_out,
    float* __restrict__ out)
{
    const int b   = blockIdx.x;
    const int tid = threadIdx.x;
    const int w   = tid >> 6;
    const int l   = tid & 63;
    const int s   = l & 3;
    const int e   = (w << 4) | (l >> 2);
    const int co  = s << 5;                       // column offset (floats)

    __shared__ __align__(16) uint32_t h1p[2][HDIM / 2];   // h1 f16 pairs, dbuf
    __shared__ __align__(16) uint32_t h2p[2][HDIM / 2];   // h2 f16 pairs, dbuf
    __shared__ __align__(16) float4 bct2[HDIM];   // per-element L2 biases
    __shared__ float pbuf[2][8];                  // per-wave out partials, dbuf

    // ---- one-time: weight slices -> 48 named uint4 (192 VGPRs), fenced
    uint4 m1_00,m1_01,m1_02,m1_03, m1_10,m1_11,m1_12,m1_13;   // W_hh1
    uint4 m1_20,m1_21,m1_22,m1_23, m1_30,m1_31,m1_32,m1_33;
    uint4 m2_00,m2_01,m2_02,m2_03, m2_10,m2_11,m2_12,m2_13;   // W_ih2
    uint4 m2_20,m2_21,m2_22,m2_23, m2_30,m2_31,m2_32,m2_33;
    uint4 m3_00,m3_01,m3_02,m3_03, m3_10,m3_11,m3_12,m3_13;   // W_hh2
    uint4 m3_20,m3_21,m3_22,m3_23, m3_30,m3_31,m3_32,m3_33;
    {
        const float* p = W_hh1 + e * HDIM + co;
        ROW(m1_00,m1_01,m1_02,m1_03, p);
        ROW(m1_10,m1_11,m1_12,m1_13, p + 128 * HDIM);
        ROW(m1_20,m1_21,m1_22,m1_23, p + 256 * HDIM);
        ROW(m1_30,m1_31,m1_32,m1_33, p + 384 * HDIM);
        p = W_ih2 + e * HDIM + co;
        ROW(m2_00,m2_01,m2_02,m2_03, p);
        ROW(m2_10,m2_11,m2_12,m2_13, p + 128 * HDIM);
        ROW(m2_20,m2_21,m2_22,m2_23, p + 256 * HDIM);
        ROW(m2_30,m2_31,m2_32,m2_33, p + 384 * HDIM);
        p = W_hh2 + e * HDIM + co;
        ROW(m3_00,m3_01,m3_02,m3_03, p);
        ROW(m3_10,m3_11,m3_12,m3_13, p + 128 * HDIM);
        ROW(m3_20,m3_21,m3_22,m3_23, p + 256 * HDIM);
        ROW(m3_30,m3_31,m3_32,m3_33, p + 384 * HDIM);
    }

    // ---- one-time: L1 bias / x-weight in persistent registers (8 regs —
    // epi1 is dot-overlapped, so these must not carry an LDS-read wait);
    // L2 biases in LDS (epi2 runs post-dots where a table read is cheap).
    const float b1i = b_ih1[e]       + b_hh1[e];
    const float b1f = b_ih1[e + 128] + b_hh1[e + 128];
    const float b1g = b_ih1[e + 256] + b_hh1[e + 256];
    const float b1o = b_ih1[e + 384] + b_hh1[e + 384];
    const float wxi = W_ih1[e],       wxf = W_ih1[e + 128];
    const float wxg = W_ih1[e + 256], wxo = W_ih1[e + 384];
    if (tid < HDIM) {
        bct2[tid] = make_float4(
            b_ih2[tid]       + b_hh2[tid],
            b_ih2[tid + 128] + b_hh2[tid + 128],
            b_ih2[tid + 256] + b_hh2[tid + 256],
            b_ih2[tid + 384] + b_hh2[tid + 384]);
    }
    const float wo = (s == 0) ? W_out[e] : 0.0f;
    const float bo = b_out[0];

    float c1 = 0.f, c2 = 0.f;                      // replicated across 4 lanes

    if (tid < HDIM / 2) {
        h1p[0][tid] = 0u; h1p[1][tid] = 0u;        // h1(-1) = h2(-1) = 0
        h2p[0][tid] = 0u; h2p[1][tid] = 0u;
    }
    __syncthreads();

    const float* xb = x + b * T_STEPS;
    float*       ob = out + b * T_STEPS;
    float x_cur = xb[0];

    // Iteration k (k = 0..T): computes h1(k) and h2(k-1)/out(k-1).
    for (int k = 0; k <= T_STEPS; ++k) {
        const int rb = k & 1, wbuf = rb ^ 1;
        float x_nxt = xb[(k + 1 < T_STEPS) ? (k + 1) : (T_STEPS - 1)];

        // ---- fused dot block: 192 dot2, 8 indep acc chains.
        // Order m1 -> m2 -> m3: epi1 needs only the a-chains, so it can
        // overlap the m2/m3 dots in the scheduler's hands.
        const uint4* H1 = (const uint4*)h1p[rb];
        const uint4* H2 = (const uint4*)h2p[rb];
        uint4 Ha0 = H1[4*s+0], Ha1 = H1[4*s+1];   // h1 cols [co, co+16)
        uint4 Hb0 = H1[4*s+2], Hb1 = H1[4*s+3];   // h1 cols [co+16, co+32)
        uint4 Hc0 = H2[4*s+0], Hc1 = H2[4*s+1];   // h2 halves
        uint4 Hd0 = H2[4*s+2], Hd1 = H2[4*s+3];
        float a0=0.f,a1=0.f,a2=0.f,a3=0.f, q0=0.f,q1=0.f,q2=0.f,q3=0.f;
        DOT8(m1_00,m1_01, Ha0,Ha1, a0); DOT8(m1_10,m1_11, Ha0,Ha1, a1);
        DOT8(m1_20,m1_21, Ha0,Ha1, a2); DOT8(m1_30,m1_31, Ha0,Ha1, a3);
        DOT8(m1_02,m1_03, Hb0,Hb1, a0); DOT8(m1_12,m1_13, Hb0,Hb1, a1);
        DOT8(m1_22,m1_23, Hb0,Hb1, a2); DOT8(m1_32,m1_33, Hb0,Hb1, a3);
        DOT8(m2_00,m2_01, Ha0,Ha1, q0); DOT8(m2_10,m2_11, Ha0,Ha1, q1);
        DOT8(m2_20,m2_21, Ha0,Ha1, q2); DOT8(m2_30,m2_31, Ha0,Ha1, q3);
        DOT8(m2_02,m2_03, Hb0,Hb1, q0); DOT8(m2_12,m2_13, Hb0,Hb1, q1);
        DOT8(m2_22,m2_23, Hb0,Hb1, q2); DOT8(m2_32,m2_33, Hb0,Hb1, q3);
        DOT8(m3_00,m3_01, Hc0,Hc1, q0); DOT8(m3_10,m3_11, Hc0,Hc1, q1);
        DOT8(m3_20,m3_21, Hc0,Hc1, q2); DOT8(m3_30,m3_31, Hc0,Hc1, q3);
        DOT8(m3_02,m3_03, Hd0,Hd1, q0); DOT8(m3_12,m3_13, Hd0,Hd1, q1);
        DOT8(m3_22,m3_23, Hd0,Hd1, q2); DOT8(m3_32,m3_33, Hd0,Hd1, q3);

        // ---- store out(k-2): moved off the step head (independent of the
        // dots; runs while the q-chains finish)
        if (k >= 2 && tid < 8) {
            float ssum = pbuf[wbuf][tid];
            ssum += __shfl_xor(ssum, 1, 64);
            ssum += __shfl_xor(ssum, 2, 64);
            ssum += __shfl_xor(ssum, 4, 64);
            if (tid == 0) ob[k - 2] = ssum + bo;
        }

        // ---- epilogue 1: h1(k)  (bias/x-weight in registers, no LDS wait)
        a0 = red2(a0); a1 = red2(a1); a2 = red2(a2); a3 = red2(a3);
        float gi = actf(a0 + fmaf(x_cur, wxi, b1i), 1.0f);
        float gf = actf(a1 + fmaf(x_cur, wxf, b1f), 1.0f);
        float gg = actf(a2 + fmaf(x_cur, wxg, b1g), 2.0f);
        float go = actf(a3 + fmaf(x_cur, wxo, b1o), 1.0f);
        c1 = fmaf(gf, c1, gi * gg);
        float h1v = go * actf(c1, 2.0f);
        if (s == 0) ((uint16_t*)h1p[wbuf])[e] = f2h(h1v);

        // ---- epilogue 2: h2(k-1) + out(k-1) partial (skip at k=0)
        if (k > 0) {
            float4 B2 = bct2[e];
            q0 = red2(q0); q1 = red2(q1); q2 = red2(q2); q3 = red2(q3);
            float hi = actf(q0 + B2.x, 1.0f);
            float hf = actf(q1 + B2.y, 1.0f);
            float hg = actf(q2 + B2.z, 2.0f);
            float ho = actf(q3 + B2.w, 1.0f);
            c2 = fmaf(hf, c2, hi * hg);
            float h2v = ho * actf(c2, 2.0f);
            if (s == 0) ((uint16_t*)h2p[wbuf])[e] = f2h(h2v);
            float part = wo * h2v;                 // wo==0 on s!=0 lanes
            part += __shfl_xor(part, 4,  64);
            part += __shfl_xor(part, 8,  64);
            part += __shfl_xor(part, 16, 64);
            part += __shfl_xor(part, 32, 64);
            if (l == 0) pbuf[rb][w] = part;
        }
        __syncthreads();   // single barrier: publish h1(k), h2(k-1), partials
        x_cur = x_nxt;
    }

    // ---- drain: out(T-1) partials were published at k=T (parity T&1)
    if (tid < 8) {
        float ssum = pbuf[T_STEPS & 1][tid];
        ssum += __shfl_xor(ssum, 1, 64);
        ssum += __shfl_xor(ssum, 2, 64);
        ssum += __shfl_xor(ssum, 4, 64);
        if (tid == 0) ob[T_STEPS - 1] = ssum + bo;
    }
}

extern "C" void kernel_launch(void* const* d_in, const int* in_sizes, int n_in,
                              void* d_out, int out_size, void* d_ws, size_t ws_size,
                              hipStream_t stream) {
    const float* x     = (const float*)d_in[0];
    const float* W_ih1 = (const float*)d_in[1];
    const float* W_hh1 = (const float*)d_in[2];
    const float* b_ih1 = (const float*)d_in[3];
    const float* b_hh1 = (const float*)d_in[4];
    const float* W_ih2 = (const float*)d_in[5];
    const float* W_hh2 = (const float*)d_in[6];
    const float* b_ih2 = (const float*)d_in[7];
    const float* b_hh2 = (const float*)d_in[8];
    const float* W_out = (const float*)d_in[9];
    const float* b_out = (const float*)d_in[10];
    float* out = (float*)d_out;

    const int B = in_sizes[0] / T_STEPS;   // 256
    hipLaunchKernelGGL(lstm_persistent, dim3(B), dim3(NT), 0, stream,
                       x, W_ih1, W_hh1, b_ih1, b_hh1,
                       W_ih2, W_hh2, b_ih2, b_hh2, W_out, b_out, out);
}

// Round 13
// 1588.023 us; speedup vs baseline: 2.6793x; 1.0037x over previous
//
#include <hip/hip_runtime.h>
#include <hip/hip_fp16.h>
#include <stdint.h>

#define T_STEPS 1024
#define HDIM    128
#define NT      512

// K-sliced, single-barrier pipelined design (R13 = R12 + AGPR-alloc-0 +
// phased H loads):
//   wave w = tid>>6 (0..7), lane l = tid&63
//   slice   s = l & 3        -> h columns [32s, 32s+32)
//   element e = 16w + (l>>2) (0..127)
// Iteration k fuses: gates1(k)   = W_hh1*h1(k-1)            (+ x(k), bias)
//                    gates2(k-1) = W_ih2*h1(k-1) + W_hh2*h2(k-2)
// One 192-dot block, two epilogues, ONE barrier.
// R13 deltas vs R12 (1701 us):
//  - amdgpu_agpr_alloc(0) (guarded): every occupancy point so far reported
//    arch VGPRs = exactly half the unified budget (64/128/256) -> fixed
//    50/50 arch/AGPR split; the ~64-120 weight dwords exiled to AGPRs cost
//    a v_accvgpr shuttle per use (~500 cyc/SIMD/step of the measured
//    1400-cyc VALU excess). 0 AGPRs -> 256-reg arch budget; peak demand
//    with phased loads ~243 fits.
//  - h2 fragment loads deferred until after the m2 dots: halves the
//    post-barrier LDS burst (8->4 ds_read_b128/wave) and cuts peak live
//    regs by 16 dwords (the enabler for the 256-arch fit).
//  - epi1 placed between the h2 loads and the m3 dots: its trans-chain
//    issue fills the h2 lgkm latency.

#if defined(__has_attribute)
#if __has_attribute(amdgpu_agpr_alloc)
#define AGPR0 __attribute__((amdgpu_agpr_alloc(0)))
#else
#define AGPR0
#endif
#else
#define AGPR0
#endif

typedef _Float16 v2h __attribute__((ext_vector_type(2)));
union HU { uint32_t u; v2h v; };

__device__ __forceinline__ float dot2h(uint32_t a, uint32_t b, float c) {
    HU ua, ub; ua.u = a; ub.u = b;
    return __builtin_amdgcn_fdot2(ua.v, ub.v, c, false);  // v_dot2_f32_f16
}
__device__ __forceinline__ uint32_t packh2f(float2 e) {
    return (uint32_t)__half_as_ushort(__float2half_rn(e.x)) |
           ((uint32_t)__half_as_ushort(__float2half_rn(e.y)) << 16);
}
__device__ __forceinline__ uint16_t f2h(float f) {
    return __half_as_ushort(__float2half_rn(f));
}
// act(a,1)=sigmoid(a); act(a,2)=tanh(a)
__device__ __forceinline__ float actf(float a, float m) {
    return 1.0f - m * __builtin_amdgcn_rcpf(__expf(m * a) + 1.0f);
}
// reduce over the 4 slice-lanes (lane bits 0..1): two DPP quad-perm adds.
__device__ __forceinline__ float red2(float v) {
    int iv = __float_as_int(v);
    v += __int_as_float(__builtin_amdgcn_update_dpp(0, iv, 0xB1, 0xF, 0xF, true)); // xor1
    iv = __float_as_int(v);
    v += __int_as_float(__builtin_amdgcn_update_dpp(0, iv, 0x4E, 0xF, 0xF, true)); // xor2
    return v;
}

#define SB() __builtin_amdgcn_sched_barrier(0)
#define PIN4(W) asm volatile("" : "+v"(W.x), "+v"(W.y), "+v"(W.z), "+v"(W.w))

// pack 32 consecutive floats at P into 4 uint4 of f16 pairs
#define SETW16(Wa, Wb, Wc, Wd, P) do { const float2* _r = (const float2*)(P); \
    Wa = make_uint4(packh2f(_r[0]),  packh2f(_r[1]),                       \
                    packh2f(_r[2]),  packh2f(_r[3]));                      \
    Wb = make_uint4(packh2f(_r[4]),  packh2f(_r[5]),                       \
                    packh2f(_r[6]),  packh2f(_r[7]));                      \
    Wc = make_uint4(packh2f(_r[8]),  packh2f(_r[9]),                       \
                    packh2f(_r[10]), packh2f(_r[11]));                     \
    Wd = make_uint4(packh2f(_r[12]), packh2f(_r[13]),                      \
                    packh2f(_r[14]), packh2f(_r[15])); } while (0)

// row pack + immediate pin + scheduling fence: caps init pressure spike.
#define ROW(Wa, Wb, Wc, Wd, P) do {                                        \
    SETW16(Wa, Wb, Wc, Wd, P);                                             \
    PIN4(Wa); PIN4(Wb); PIN4(Wc); PIN4(Wd); SB(); } while (0)

// 8 dot2s: one weight pair (2 uint4 = 16 cols) vs h pair
#define DOT8(Wa, Wb, H0, H1, acc) do {                                     \
    acc = dot2h(Wa.x, H0.x, acc); acc = dot2h(Wa.y, H0.y, acc);            \
    acc = dot2h(Wa.z, H0.z, acc); acc = dot2h(Wa.w, H0.w, acc);            \
    acc = dot2h(Wb.x, H1.x, acc); acc = dot2h(Wb.y, H1.y, acc);            \
    acc = dot2h(Wb.z, H1.z, acc); acc = dot2h(Wb.w, H1.w, acc); } while (0)

__global__ __launch_bounds__(NT)
__attribute__((amdgpu_waves_per_eu(2, 2)))
AGPR0
void lstm_persistent(
    const float* __restrict__ x,
    const float* __restrict__ W_ih1, const float* __restrict__ W_hh1,
    const float* __restrict__ b_ih1, const float* __restrict__ b_hh1,
    const float* __restrict__ W_ih2, const float* __restrict__ W_hh2,
    const float* __restrict__ b_ih2, const float* __restrict__ b_hh2,
    const float* __restrict__ W_out, const float* __restrict__ b_out,
    float* __restrict__ out)
{
    const int b   = blockIdx.x;
    const int tid = threadIdx.x;
    const int w   = tid >> 6;
    const int l   = tid & 63;
    const int s   = l & 3;
    const int e   = (w << 4) | (l >> 2);
    const int co  = s << 5;                       // column offset (floats)

    __shared__ __align__(16) uint32_t h1p[2][HDIM / 2];   // h1 f16 pairs, dbuf
    __shared__ __align__(16) uint32_t h2p[2][HDIM / 2];   // h2 f16 pairs, dbuf
    __shared__ __align__(16) float4 bct2[HDIM];   // per-element L2 biases
    __shared__ float pbuf[2][8];                  // per-wave out partials, dbuf

    // ---- one-time: weight slices -> 48 named uint4 (192 dwords), fenced
    uint4 m1_00,m1_01,m1_02,m1_03, m1_10,m1_11,m1_12,m1_13;   // W_hh1
    uint4 m1_20,m1_21,m1_22,m1_23, m1_30,m1_31,m1_32,m1_33;
    uint4 m2_00,m2_01,m2_02,m2_03, m2_10,m2_11,m2_12,m2_13;   // W_ih2
    uint4 m2_20,m2_21,m2_22,m2_23, m2_30,m2_31,m2_32,m2_33;
    uint4 m3_00,m3_01,m3_02,m3_03, m3_10,m3_11,m3_12,m3_13;   // W_hh2
    uint4 m3_20,m3_21,m3_22,m3_23, m3_30,m3_31,m3_32,m3_33;
    {
        const float* p = W_hh1 + e * HDIM + co;
        ROW(m1_00,m1_01,m1_02,m1_03, p);
        ROW(m1_10,m1_11,m1_12,m1_13, p + 128 * HDIM);
        ROW(m1_20,m1_21,m1_22,m1_23, p + 256 * HDIM);
        ROW(m1_30,m1_31,m1_32,m1_33, p + 384 * HDIM);
        p = W_ih2 + e * HDIM + co;
        ROW(m2_00,m2_01,m2_02,m2_03, p);
        ROW(m2_10,m2_11,m2_12,m2_13, p + 128 * HDIM);
        ROW(m2_20,m2_21,m2_22,m2_23, p + 256 * HDIM);
        ROW(m2_30,m2_31,m2_32,m2_33, p + 384 * HDIM);
        p = W_hh2 + e * HDIM + co;
        ROW(m3_00,m3_01,m3_02,m3_03, p);
        ROW(m3_10,m3_11,m3_12,m3_13, p + 128 * HDIM);
        ROW(m3_20,m3_21,m3_22,m3_23, p + 256 * HDIM);
        ROW(m3_30,m3_31,m3_32,m3_33, p + 384 * HDIM);
    }

    // ---- one-time: L1 bias / x-weight in persistent registers; L2 biases
    // in LDS (epi2 runs post-dots where a table read is cheap).
    const float b1i = b_ih1[e]       + b_hh1[e];
    const float b1f = b_ih1[e + 128] + b_hh1[e + 128];
    const float b1g = b_ih1[e + 256] + b_hh1[e + 256];
    const float b1o = b_ih1[e + 384] + b_hh1[e + 384];
    const float wxi = W_ih1[e],       wxf = W_ih1[e + 128];
    const float wxg = W_ih1[e + 256], wxo = W_ih1[e + 384];
    if (tid < HDIM) {
        bct2[tid] = make_float4(
            b_ih2[tid]       + b_hh2[tid],
            b_ih2[tid + 128] + b_hh2[tid + 128],
            b_ih2[tid + 256] + b_hh2[tid + 256],
            b_ih2[tid + 384] + b_hh2[tid + 384]);
    }
    const float wo = (s == 0) ? W_out[e] : 0.0f;
    const float bo = b_out[0];

    float c1 = 0.f, c2 = 0.f;                      // replicated across 4 lanes

    if (tid < HDIM / 2) {
        h1p[0][tid] = 0u; h1p[1][tid] = 0u;        // h1(-1) = h2(-1) = 0
        h2p[0][tid] = 0u; h2p[1][tid] = 0u;
    }
    __syncthreads();

    const float* xb = x + b * T_STEPS;
    float*       ob = out + b * T_STEPS;
    float x_cur = xb[0];

    // Iteration k (k = 0..T): computes h1(k) and h2(k-1)/out(k-1).
    for (int k = 0; k <= T_STEPS; ++k) {
        const int rb = k & 1, wbuf = rb ^ 1;
        float x_nxt = xb[(k + 1 < T_STEPS) ? (k + 1) : (T_STEPS - 1)];

        // ---- phase 1: h1 fragments only (4 ds_read_b128/thread — half the
        // old step-head LDS burst), then m1 + m2 dots (both consume h1).
        const uint4* H1 = (const uint4*)h1p[rb];
        uint4 Ha0 = H1[4*s+0], Ha1 = H1[4*s+1];   // h1 cols [co, co+16)
        uint4 Hb0 = H1[4*s+2], Hb1 = H1[4*s+3];   // h1 cols [co+16, co+32)
        float a0=0.f,a1=0.f,a2=0.f,a3=0.f, q0=0.f,q1=0.f,q2=0.f,q3=0.f;
        DOT8(m1_00,m1_01, Ha0,Ha1, a0); DOT8(m1_10,m1_11, Ha0,Ha1, a1);
        DOT8(m1_20,m1_21, Ha0,Ha1, a2); DOT8(m1_30,m1_31, Ha0,Ha1, a3);
        DOT8(m1_02,m1_03, Hb0,Hb1, a0); DOT8(m1_12,m1_13, Hb0,Hb1, a1);
        DOT8(m1_22,m1_23, Hb0,Hb1, a2); DOT8(m1_32,m1_33, Hb0,Hb1, a3);
        DOT8(m2_00,m2_01, Ha0,Ha1, q0); DOT8(m2_10,m2_11, Ha0,Ha1, q1);
        DOT8(m2_20,m2_21, Ha0,Ha1, q2); DOT8(m2_30,m2_31, Ha0,Ha1, q3);
        DOT8(m2_02,m2_03, Hb0,Hb1, q0); DOT8(m2_12,m2_13, Hb0,Hb1, q1);
        DOT8(m2_22,m2_23, Hb0,Hb1, q2); DOT8(m2_32,m2_33, Hb0,Hb1, q3);

        // ---- phase 2: issue h2 reads; their latency is filled by the
        // out(k-2) store and epi1 below before m3 consumes them.
        const uint4* H2 = (const uint4*)h2p[rb];
        uint4 Hc0 = H2[4*s+0], Hc1 = H2[4*s+1];
        uint4 Hd0 = H2[4*s+2], Hd1 = H2[4*s+3];

        // ---- store out(k-2): independent work under the h2 lgkm wait
        if (k >= 2 && tid < 8) {
            float ssum = pbuf[wbuf][tid];
            ssum += __shfl_xor(ssum, 1, 64);
            ssum += __shfl_xor(ssum, 2, 64);
            ssum += __shfl_xor(ssum, 4, 64);
            if (tid == 0) ob[k - 2] = ssum + bo;
        }

        // ---- epilogue 1: h1(k) — trans chains overlap the h2 latency;
        // frees the a-registers before m3 peaks.
        a0 = red2(a0); a1 = red2(a1); a2 = red2(a2); a3 = red2(a3);
        float gi = actf(a0 + fmaf(x_cur, wxi, b1i), 1.0f);
        float gf = actf(a1 + fmaf(x_cur, wxf, b1f), 1.0f);
        float gg = actf(a2 + fmaf(x_cur, wxg, b1g), 2.0f);
        float go = actf(a3 + fmaf(x_cur, wxo, b1o), 1.0f);
        c1 = fmaf(gf, c1, gi * gg);
        float h1v = go * actf(c1, 2.0f);
        if (s == 0) ((uint16_t*)h1p[wbuf])[e] = f2h(h1v);

        // ---- phase 3: m3 dots (h2 x W_hh2)
        DOT8(m3_00,m3_01, Hc0,Hc1, q0); DOT8(m3_10,m3_11, Hc0,Hc1, q1);
        DOT8(m3_20,m3_21, Hc0,Hc1, q2); DOT8(m3_30,m3_31, Hc0,Hc1, q3);
        DOT8(m3_02,m3_03, Hd0,Hd1, q0); DOT8(m3_12,m3_13, Hd0,Hd1, q1);
        DOT8(m3_22,m3_23, Hd0,Hd1, q2); DOT8(m3_32,m3_33, Hd0,Hd1, q3);

        // ---- epilogue 2: h2(k-1) + out(k-1) partial (skip at k=0)
        if (k > 0) {
            float4 B2 = bct2[e];
            q0 = red2(q0); q1 = red2(q1); q2 = red2(q2); q3 = red2(q3);
            float hi = actf(q0 + B2.x, 1.0f);
            float hf = actf(q1 + B2.y, 1.0f);
            float hg = actf(q2 + B2.z, 2.0f);
            float ho = actf(q3 + B2.w, 1.0f);
            c2 = fmaf(hf, c2, hi * hg);
            float h2v = ho * actf(c2, 2.0f);
            if (s == 0) ((uint16_t*)h2p[wbuf])[e] = f2h(h2v);
            float part = wo * h2v;                 // wo==0 on s!=0 lanes
            part += __shfl_xor(part, 4,  64);
            part += __shfl_xor(part, 8,  64);
            part += __shfl_xor(part, 16, 64);
            part += __shfl_xor(part, 32, 64);
            if (l == 0) pbuf[rb][w] = part;
        }
        __syncthreads();   // single barrier: publish h1(k), h2(k-1), partials
        x_cur = x_nxt;
    }

    // ---- drain: out(T-1) partials were published at k=T (parity T&1)
    if (tid < 8) {
        float ssum = pbuf[T_STEPS & 1][tid];
        ssum += __shfl_xor(ssum, 1, 64);
        ssum += __shfl_xor(ssum, 2, 64);
        ssum += __shfl_xor(ssum, 4, 64);
        if (tid == 0) ob[T_STEPS - 1] = ssum + bo;
    }
}

extern "C" void kernel_launch(void* const* d_in, const int* in_sizes, int n_in,
                              void* d_out, int out_size, void* d_ws, size_t ws_size,
                              hipStream_t stream) {
    const float* x     = (const float*)d_in[0];
    const float* W_ih1 = (const float*)d_in[1];
    const float* W_hh1 = (const float*)d_in[2];
    const float* b_ih1 = (const float*)d_in[3];
    const float* b_hh1 = (const float*)d_in[4];
    const float* W_ih2 = (const float*)d_in[5];
    const float* W_hh2 = (const float*)d_in[6];
    const float* b_ih2 = (const float*)d_in[7];
    const float* b_hh2 = (const float*)d_in[8];
    const float* W_out = (const float*)d_in[9];
    const float* b_out = (const float*)d_in[10];
    float* out = (float*)d_out;

    const int B = in_sizes[0] / T_STEPS;   // 256
    hipLaunchKernelGGL(lstm_persistent, dim3(B), dim3(NT), 0, stream,
                       x, W_ih1, W_hh1, b_ih1, b_hh1,
                       W_ih2, W_hh2, b_ih2, b_hh2, W_out, b_out, out);
}

// Round 14
// 1538.219 us; speedup vs baseline: 2.7660x; 1.0324x over previous
//
#include <hip/hip_runtime.h>
#include <hip/hip_fp16.h>
#include <stdint.h>

#define T_STEPS 1024
#define HDIM    128
#define NT      512

// K-sliced, single-barrier pipelined design (R14 = R13 + exp2 prescale +
// reg-resident L2 biases):
//   wave w = tid>>6 (0..7), lane l = tid&63
//   slice   s = l & 3        -> h columns [32s, 32s+32)
//   element e = 16w + (l>>2) (0..127)
// Iteration k fuses: gates1(k)   = W_hh1*h1(k-1)            (+ x(k), bias)
//                    gates2(k-1) = W_ih2*h1(k-1) + W_hh2*h2(k-2)
// One 192-dot block, two epilogues, ONE barrier.
// R14 deltas vs R13 (1675 us):
//  - all weights/biases pre-scaled by log2(e) at init -> activations use
//    raw v_exp_f32 (exp2) with no per-use *log2e mul (6 v_mul/thread/step).
//  - L2 biases in 4 persistent regs (bct2 LDS table dropped): removes a
//    ds_read_b128 + lgkm wait from epi2.
// Register-fight verdict (R6-R13): per-SIMD unified file = 512 regs;
// weights = 75% of the CU file; compiler caps arch at ~128/wave at
// 2 waves/SIMD and shuttles the rest via AGPR. Every public knob tried;
// all neutral. The shuttle + dot2 issue rate are the residual.

typedef _Float16 v2h __attribute__((ext_vector_type(2)));
union HU { uint32_t u; v2h v; };

#define SCL  1.44269504088896340736f   // log2(e)
#define K2C  2.88538008177792681472f   // 2*log2(e)

__device__ __forceinline__ float dot2h(uint32_t a, uint32_t b, float c) {
    HU ua, ub; ua.u = a; ub.u = b;
    return __builtin_amdgcn_fdot2(ua.v, ub.v, c, false);  // v_dot2_f32_f16
}
__device__ __forceinline__ uint32_t packh2s(float2 e) {   // pre-scaled pack
    return (uint32_t)__half_as_ushort(__float2half_rn(e.x * SCL)) |
           ((uint32_t)__half_as_ushort(__float2half_rn(e.y * SCL)) << 16);
}
__device__ __forceinline__ uint16_t f2h(float f) {
    return __half_as_ushort(__float2half_rn(f));
}
// Pre-scaled activations: input a2 = a*log2e.
// act2(a2,1) = sigmoid(a);  act2(a2,2) = tanh(a).  exp2 = raw v_exp_f32.
__device__ __forceinline__ float act2(float a2, float m) {
    return 1.0f - m * __builtin_amdgcn_rcpf(
        __builtin_amdgcn_exp2f(m * a2) + 1.0f);
}
// tanh for cell state (natural domain): one const mul folds 2*log2e.
__device__ __forceinline__ float tanhc(float c) {
    return 1.0f - 2.0f * __builtin_amdgcn_rcpf(
        __builtin_amdgcn_exp2f(K2C * c) + 1.0f);
}
// reduce over the 4 slice-lanes (lane bits 0..1): two DPP quad-perm adds.
__device__ __forceinline__ float red2(float v) {
    int iv = __float_as_int(v);
    v += __int_as_float(__builtin_amdgcn_update_dpp(0, iv, 0xB1, 0xF, 0xF, true)); // xor1
    iv = __float_as_int(v);
    v += __int_as_float(__builtin_amdgcn_update_dpp(0, iv, 0x4E, 0xF, 0xF, true)); // xor2
    return v;
}

#define SB() __builtin_amdgcn_sched_barrier(0)
#define PIN4(W) asm volatile("" : "+v"(W.x), "+v"(W.y), "+v"(W.z), "+v"(W.w))

// pack 32 consecutive floats at P into 4 uint4 of pre-scaled f16 pairs
#define SETW16(Wa, Wb, Wc, Wd, P) do { const float2* _r = (const float2*)(P); \
    Wa = make_uint4(packh2s(_r[0]),  packh2s(_r[1]),                       \
                    packh2s(_r[2]),  packh2s(_r[3]));                      \
    Wb = make_uint4(packh2s(_r[4]),  packh2s(_r[5]),                       \
                    packh2s(_r[6]),  packh2s(_r[7]));                      \
    Wc = make_uint4(packh2s(_r[8]),  packh2s(_r[9]),                       \
                    packh2s(_r[10]), packh2s(_r[11]));                     \
    Wd = make_uint4(packh2s(_r[12]), packh2s(_r[13]),                      \
                    packh2s(_r[14]), packh2s(_r[15])); } while (0)

// row pack + immediate pin + scheduling fence: caps init pressure spike.
#define ROW(Wa, Wb, Wc, Wd, P) do {                                        \
    SETW16(Wa, Wb, Wc, Wd, P);                                             \
    PIN4(Wa); PIN4(Wb); PIN4(Wc); PIN4(Wd); SB(); } while (0)

// 8 dot2s: one weight pair (2 uint4 = 16 cols) vs h pair
#define DOT8(Wa, Wb, H0, H1, acc) do {                                     \
    acc = dot2h(Wa.x, H0.x, acc); acc = dot2h(Wa.y, H0.y, acc);            \
    acc = dot2h(Wa.z, H0.z, acc); acc = dot2h(Wa.w, H0.w, acc);            \
    acc = dot2h(Wb.x, H1.x, acc); acc = dot2h(Wb.y, H1.y, acc);            \
    acc = dot2h(Wb.z, H1.z, acc); acc = dot2h(Wb.w, H1.w, acc); } while (0)

__global__ __launch_bounds__(NT)
__attribute__((amdgpu_waves_per_eu(2, 2)))
void lstm_persistent(
    const float* __restrict__ x,
    const float* __restrict__ W_ih1, const float* __restrict__ W_hh1,
    const float* __restrict__ b_ih1, const float* __restrict__ b_hh1,
    const float* __restrict__ W_ih2, const float* __restrict__ W_hh2,
    const float* __restrict__ b_ih2, const float* __restrict__ b_hh2,
    const float* __restrict__ W_out, const float* __restrict__ b_out,
    float* __restrict__ out)
{
    const int b   = blockIdx.x;
    const int tid = threadIdx.x;
    const int w   = tid >> 6;
    const int l   = tid & 63;
    const int s   = l & 3;
    const int e   = (w << 4) | (l >> 2);
    const int co  = s << 5;                       // column offset (floats)

    __shared__ __align__(16) uint32_t h1p[2][HDIM / 2];   // h1 f16 pairs, dbuf
    __shared__ __align__(16) uint32_t h2p[2][HDIM / 2];   // h2 f16 pairs, dbuf
    __shared__ float pbuf[2][8];                  // per-wave out partials, dbuf

    // ---- one-time: weight slices -> 48 named uint4 (192 dwords), fenced
    uint4 m1_00,m1_01,m1_02,m1_03, m1_10,m1_11,m1_12,m1_13;   // W_hh1
    uint4 m1_20,m1_21,m1_22,m1_23, m1_30,m1_31,m1_32,m1_33;
    uint4 m2_00,m2_01,m2_02,m2_03, m2_10,m2_11,m2_12,m2_13;   // W_ih2
    uint4 m2_20,m2_21,m2_22,m2_23, m2_30,m2_31,m2_32,m2_33;
    uint4 m3_00,m3_01,m3_02,m3_03, m3_10,m3_11,m3_12,m3_13;   // W_hh2
    uint4 m3_20,m3_21,m3_22,m3_23, m3_30,m3_31,m3_32,m3_33;
    {
        const float* p = W_hh1 + e * HDIM + co;
        ROW(m1_00,m1_01,m1_02,m1_03, p);
        ROW(m1_10,m1_11,m1_12,m1_13, p + 128 * HDIM);
        ROW(m1_20,m1_21,m1_22,m1_23, p + 256 * HDIM);
        ROW(m1_30,m1_31,m1_32,m1_33, p + 384 * HDIM);
        p = W_ih2 + e * HDIM + co;
        ROW(m2_00,m2_01,m2_02,m2_03, p);
        ROW(m2_10,m2_11,m2_12,m2_13, p + 128 * HDIM);
        ROW(m2_20,m2_21,m2_22,m2_23, p + 256 * HDIM);
        ROW(m2_30,m2_31,m2_32,m2_33, p + 384 * HDIM);
        p = W_hh2 + e * HDIM + co;
        ROW(m3_00,m3_01,m3_02,m3_03, p);
        ROW(m3_10,m3_11,m3_12,m3_13, p + 128 * HDIM);
        ROW(m3_20,m3_21,m3_22,m3_23, p + 256 * HDIM);
        ROW(m3_30,m3_31,m3_32,m3_33, p + 384 * HDIM);
    }

    // ---- one-time: ALL biases / x-weights pre-scaled by log2e, in regs
    const float b1i = (b_ih1[e]       + b_hh1[e])       * SCL;
    const float b1f = (b_ih1[e + 128] + b_hh1[e + 128]) * SCL;
    const float b1g = (b_ih1[e + 256] + b_hh1[e + 256]) * SCL;
    const float b1o = (b_ih1[e + 384] + b_hh1[e + 384]) * SCL;
    const float wxi = W_ih1[e]       * SCL, wxf = W_ih1[e + 128] * SCL;
    const float wxg = W_ih1[e + 256] * SCL, wxo = W_ih1[e + 384] * SCL;
    const float b2i = (b_ih2[e]       + b_hh2[e])       * SCL;
    const float b2f = (b_ih2[e + 128] + b_hh2[e + 128]) * SCL;
    const float b2g = (b_ih2[e + 256] + b_hh2[e + 256]) * SCL;
    const float b2o = (b_ih2[e + 384] + b_hh2[e + 384]) * SCL;
    const float wo = (s == 0) ? W_out[e] : 0.0f;
    const float bo = b_out[0];

    float c1 = 0.f, c2 = 0.f;                      // replicated across 4 lanes

    if (tid < HDIM / 2) {
        h1p[0][tid] = 0u; h1p[1][tid] = 0u;        // h1(-1) = h2(-1) = 0
        h2p[0][tid] = 0u; h2p[1][tid] = 0u;
    }
    __syncthreads();

    const float* xb = x + b * T_STEPS;
    float*       ob = out + b * T_STEPS;
    float x_cur = xb[0];

    // Iteration k (k = 0..T): computes h1(k) and h2(k-1)/out(k-1).
    for (int k = 0; k <= T_STEPS; ++k) {
        const int rb = k & 1, wbuf = rb ^ 1;
        float x_nxt = xb[(k + 1 < T_STEPS) ? (k + 1) : (T_STEPS - 1)];

        // ---- phase 1: h1 fragments, then m1 + m2 dots (both consume h1).
        const uint4* H1 = (const uint4*)h1p[rb];
        uint4 Ha0 = H1[4*s+0], Ha1 = H1[4*s+1];   // h1 cols [co, co+16)
        uint4 Hb0 = H1[4*s+2], Hb1 = H1[4*s+3];   // h1 cols [co+16, co+32)
        float a0=0.f,a1=0.f,a2=0.f,a3=0.f, q0=0.f,q1=0.f,q2=0.f,q3=0.f;
        DOT8(m1_00,m1_01, Ha0,Ha1, a0); DOT8(m1_10,m1_11, Ha0,Ha1, a1);
        DOT8(m1_20,m1_21, Ha0,Ha1, a2); DOT8(m1_30,m1_31, Ha0,Ha1, a3);
        DOT8(m1_02,m1_03, Hb0,Hb1, a0); DOT8(m1_12,m1_13, Hb0,Hb1, a1);
        DOT8(m1_22,m1_23, Hb0,Hb1, a2); DOT8(m1_32,m1_33, Hb0,Hb1, a3);
        DOT8(m2_00,m2_01, Ha0,Ha1, q0); DOT8(m2_10,m2_11, Ha0,Ha1, q1);
        DOT8(m2_20,m2_21, Ha0,Ha1, q2); DOT8(m2_30,m2_31, Ha0,Ha1, q3);
        DOT8(m2_02,m2_03, Hb0,Hb1, q0); DOT8(m2_12,m2_13, Hb0,Hb1, q1);
        DOT8(m2_22,m2_23, Hb0,Hb1, q2); DOT8(m2_32,m2_33, Hb0,Hb1, q3);

        // ---- phase 2: issue h2 reads; latency filled by out-store + epi1.
        const uint4* H2 = (const uint4*)h2p[rb];
        uint4 Hc0 = H2[4*s+0], Hc1 = H2[4*s+1];
        uint4 Hd0 = H2[4*s+2], Hd1 = H2[4*s+3];

        // ---- store out(k-2): independent work under the h2 lgkm wait
        if (k >= 2 && tid < 8) {
            float ssum = pbuf[wbuf][tid];
            ssum += __shfl_xor(ssum, 1, 64);
            ssum += __shfl_xor(ssum, 2, 64);
            ssum += __shfl_xor(ssum, 4, 64);
            if (tid == 0) ob[k - 2] = ssum + bo;
        }

        // ---- epilogue 1: h1(k) — pre-scaled domain, raw v_exp activations
        a0 = red2(a0); a1 = red2(a1); a2 = red2(a2); a3 = red2(a3);
        float gi = act2(a0 + fmaf(x_cur, wxi, b1i), 1.0f);
        float gf = act2(a1 + fmaf(x_cur, wxf, b1f), 1.0f);
        float gg = act2(a2 + fmaf(x_cur, wxg, b1g), 2.0f);
        float go = act2(a3 + fmaf(x_cur, wxo, b1o), 1.0f);
        c1 = fmaf(gf, c1, gi * gg);
        float h1v = go * tanhc(c1);
        if (s == 0) ((uint16_t*)h1p[wbuf])[e] = f2h(h1v);

        // ---- phase 3: m3 dots (h2 x W_hh2)
        DOT8(m3_00,m3_01, Hc0,Hc1, q0); DOT8(m3_10,m3_11, Hc0,Hc1, q1);
        DOT8(m3_20,m3_21, Hc0,Hc1, q2); DOT8(m3_30,m3_31, Hc0,Hc1, q3);
        DOT8(m3_02,m3_03, Hd0,Hd1, q0); DOT8(m3_12,m3_13, Hd0,Hd1, q1);
        DOT8(m3_22,m3_23, Hd0,Hd1, q2); DOT8(m3_32,m3_33, Hd0,Hd1, q3);

        // ---- epilogue 2: h2(k-1) + out(k-1) partial (skip at k=0)
        if (k > 0) {
            q0 = red2(q0); q1 = red2(q1); q2 = red2(q2); q3 = red2(q3);
            float hi = act2(q0 + b2i, 1.0f);
            float hf = act2(q1 + b2f, 1.0f);
            float hg = act2(q2 + b2g, 2.0f);
            float ho = act2(q3 + b2o, 1.0f);
            c2 = fmaf(hf, c2, hi * hg);
            float h2v = ho * tanhc(c2);
            if (s == 0) ((uint16_t*)h2p[wbuf])[e] = f2h(h2v);
            float part = wo * h2v;                 // wo==0 on s!=0 lanes
            part += __shfl_xor(part, 4,  64);
            part += __shfl_xor(part, 8,  64);
            part += __shfl_xor(part, 16, 64);
            part += __shfl_xor(part, 32, 64);
            if (l == 0) pbuf[rb][w] = part;
        }
        __syncthreads();   // single barrier: publish h1(k), h2(k-1), partials
        x_cur = x_nxt;
    }

    // ---- drain: out(T-1) partials were published at k=T (parity T&1)
    if (tid < 8) {
        float ssum = pbuf[T_STEPS & 1][tid];
        ssum += __shfl_xor(ssum, 1, 64);
        ssum += __shfl_xor(ssum, 2, 64);
        ssum += __shfl_xor(ssum, 4, 64);
        if (tid == 0) ob[T_STEPS - 1] = ssum + bo;
    }
}

extern "C" void kernel_launch(void* const* d_in, const int* in_sizes, int n_in,
                              void* d_out, int out_size, void* d_ws, size_t ws_size,
                              hipStream_t stream) {
    const float* x     = (const float*)d_in[0];
    const float* W_ih1 = (const float*)d_in[1];
    const float* W_hh1 = (const float*)d_in[2];
    const float* b_ih1 = (const float*)d_in[3];
    const float* b_hh1 = (const float*)d_in[4];
    const float* W_ih2 = (const float*)d_in[5];
    const float* W_hh2 = (const float*)d_in[6];
    const float* b_ih2 = (const float*)d_in[7];
    const float* b_hh2 = (const float*)d_in[8];
    const float* W_out = (const float*)d_in[9];
    const float* b_out = (const float*)d_in[10];
    float* out = (float*)d_out;

    const int B = in_sizes[0] / T_STEPS;   // 256
    hipLaunchKernelGGL(lstm_persistent, dim3(B), dim3(NT), 0, stream,
                       x, W_ih1, W_hh1, b_ih1, b_hh1,
                       W_ih2, W_hh2, b_ih2, b_hh2, W_out, b_out, out);
}